// Round 6
// baseline (360.599 us; speedup 1.0000x reference)
//
#include <hip/hip_runtime.h>
#include <cstddef>

#define NSTATE 1280
#define TCACHE 448
#define NBATCH 128
#define NHEAD  20
#define HDIM   64
#define NT     8
#define RPC    (TCACHE / NT)   // 56 rows per chunk

typedef float f4 __attribute__((ext_vector_type(4)));
typedef float f32x4 __attribute__((ext_vector_type(4)));
typedef short bf16x8 __attribute__((ext_vector_type(8)));
typedef unsigned short u16;

__device__ __forceinline__ u16 f2bf(float f) {
    unsigned u = __builtin_bit_cast(unsigned, f);
    u += 0x7fff + ((u >> 16) & 1);          // RTN-even (finite inputs)
    return (u16)(u >> 16);
}

// load 8 consecutive fp32, convert to bf16x8 (A-fragment, k-contiguous)
__device__ __forceinline__ bf16x8 ld_a_bf16(const float* __restrict__ p) {
    float4 a0 = *(const float4*)p;
    float4 a1 = *(const float4*)(p + 4);
    bf16x8 r;
    r[0] = (short)f2bf(a0.x); r[1] = (short)f2bf(a0.y);
    r[2] = (short)f2bf(a0.z); r[3] = (short)f2bf(a0.w);
    r[4] = (short)f2bf(a1.x); r[5] = (short)f2bf(a1.y);
    r[6] = (short)f2bf(a1.z); r[7] = (short)f2bf(a1.w);
    return r;
}

// B-fragment from W[k][n] row-major: 8 strided scalar loads down column `col`
__device__ __forceinline__ bf16x8 ld_b_bf16(const float* __restrict__ W,
                                            int kk, int col) {
    bf16x8 r;
    #pragma unroll
    for (int j = 0; j < 8; ++j)
        r[j] = (short)f2bf(W[(size_t)(kk + j) * NSTATE + col]);
    return r;
}

// ---------------------------------------------------------------------------
// MFMA projection q/k/v: C[128][1280] = x @ W (+bias), no LDS, no pre-cvt.
// grid (20, 3), 512 threads = 8 waves; wave w: m-half = w>>2 (4 mf tiles),
// n-slice = (w&3)*16. A/B converted fp32->bf16 in registers on the fly.
// A-frag: row=lane&15, k=(lane>>4)*8+j. D-frag: col=lane&15, row=(lane>>4)*4+reg.
// ---------------------------------------------------------------------------
__global__ void __launch_bounds__(512) proj_mfma_kernel(
    const float* __restrict__ x,
    const float* __restrict__ Wq, const float* __restrict__ bq,
    const float* __restrict__ Wk,
    const float* __restrict__ Wv, const float* __restrict__ bv,
    float* __restrict__ q_ws, float* __restrict__ kout, float* __restrict__ vout)
{
    const int nt = blockIdx.x, z = blockIdx.y;
    const float* W = (z == 0) ? Wq : (z == 1) ? Wk : Wv;
    const int w = threadIdx.x >> 6, l = threadIdx.x & 63;
    const int mh = w >> 2, ns = w & 3;
    const int col = nt * 64 + ns * 16 + (l & 15);
    const int kg = l >> 4;
    f32x4 acc[4] = {};

    for (int ks = 0; ks < NSTATE; ks += 32) {
        const int kk = ks + kg * 8;
        const bf16x8 b = ld_b_bf16(W, kk, col);
        #pragma unroll
        for (int mf = 0; mf < 4; ++mf) {
            const int row = (mh * 4 + mf) * 16 + (l & 15);
            bf16x8 a = ld_a_bf16(x + (size_t)row * NSTATE + kk);
            acc[mf] = __builtin_amdgcn_mfma_f32_16x16x32_bf16(a, b, acc[mf], 0, 0, 0);
        }
    }
    const float bias = (z == 0) ? bq[col] : (z == 2) ? bv[col] : 0.f;
    #pragma unroll
    for (int mf = 0; mf < 4; ++mf) {
        #pragma unroll
        for (int j = 0; j < 4; ++j) {
            const int m = (mh * 4 + mf) * 16 + kg * 4 + j;
            const float val = acc[mf][j] + bias;
            if (z == 0)      q_ws[(size_t)m * NSTATE + col] = val * 0.125f;
            else if (z == 1) kout[((size_t)m * TCACHE + TCACHE - 1) * NSTATE + col] = val;
            else             vout[((size_t)m * TCACHE + TCACHE - 1) * NSTATE + col] = val;
        }
    }
}

// output projection: out = wv_bf16 @ Wo + bo. grid (20), 512 threads.
__global__ void __launch_bounds__(512) outproj_mfma_kernel(
    const u16* __restrict__ wvbf, const float* __restrict__ Wo,
    const float* __restrict__ bo, float* __restrict__ out)
{
    const int nt = blockIdx.x;
    const int w = threadIdx.x >> 6, l = threadIdx.x & 63;
    const int mh = w >> 2, ns = w & 3;
    const int col = nt * 64 + ns * 16 + (l & 15);
    const int kg = l >> 4;
    f32x4 acc[4] = {};

    for (int ks = 0; ks < NSTATE; ks += 32) {
        const int kk = ks + kg * 8;
        const bf16x8 b = ld_b_bf16(Wo, kk, col);
        #pragma unroll
        for (int mf = 0; mf < 4; ++mf) {
            const int row = (mh * 4 + mf) * 16 + (l & 15);
            bf16x8 a = *(const bf16x8*)(wvbf + (size_t)row * NSTATE + kk);
            acc[mf] = __builtin_amdgcn_mfma_f32_16x16x32_bf16(a, b, acc[mf], 0, 0, 0);
        }
    }
    const float bias = bo[col];
    #pragma unroll
    for (int mf = 0; mf < 4; ++mf)
        #pragma unroll
        for (int j = 0; j < 4; ++j)
            out[(size_t)((mh * 4 + mf) * 16 + kg * 4 + j) * NSTATE + col] =
                acc[mf][j] + bias;
}

// ---------------------------------------------------------------------------
// Fused stream kernel: per (chunk, batch) block —
//   phase 1: shift-copy K rows + per-head scores into LDS
//   phase 2: chunk-local softmax (max m_c, sum s_c, weights)
//   phase 3: shift-copy V rows + PV partial with chunk-local weights
// grid (NT, 128), 320 threads: thread = one float4 slot of a row, h = tid>>4.
// ---------------------------------------------------------------------------
__global__ void __launch_bounds__(320) fused_stream_kernel(
    const float* __restrict__ kin, const float* __restrict__ vin,
    const float* __restrict__ q_ws, const float* __restrict__ mask,
    float* __restrict__ kout, float* __restrict__ vout,
    float* __restrict__ pvp, float* __restrict__ m_ws, float* __restrict__ s_ws)
{
    const int tc = blockIdx.x, b = blockIdx.y;
    const int tid = threadIdx.x;
    const int h = tid >> 4, l = tid & 15;
    const int col = tid << 2;
    const size_t base = (size_t)b * TCACHE * NSTATE;
    const int t0 = tc * RPC;
    const int nrows = (tc == NT - 1) ? RPC - 1 : RPC;

    __shared__ float sc[NHEAD][RPC];   // raw scores, then weights

    const float4 q4 = *(const float4*)(q_ws + (size_t)b * NSTATE + col);

    // ---- phase 1: K shift-copy + scores ----
    {
        const float* src0 = kin + base + (size_t)(t0 + 1) * NSTATE + col;
        float* dst0 = kout + base + (size_t)t0 * NSTATE + col;
        #pragma unroll 4
        for (int r = 0; r < nrows; ++r) {
            f4 kv = __builtin_nontemporal_load((const f4*)(src0 + (size_t)r * NSTATE));
            __builtin_nontemporal_store(kv, (f4*)(dst0 + (size_t)r * NSTATE));
            float p = kv[0]*q4.x + kv[1]*q4.y + kv[2]*q4.z + kv[3]*q4.w;
            p += __shfl_xor(p, 1); p += __shfl_xor(p, 2);
            p += __shfl_xor(p, 4); p += __shfl_xor(p, 8);
            if (l == 0) sc[h][r] = p + mask[t0 + r];
        }
        if (tc == NT - 1) {            // row 447: already final in kout
            const f4 kv = *(const f4*)(kout + base + (size_t)(TCACHE-1) * NSTATE + col);
            float p = kv[0]*q4.x + kv[1]*q4.y + kv[2]*q4.z + kv[3]*q4.w;
            p += __shfl_xor(p, 1); p += __shfl_xor(p, 2);
            p += __shfl_xor(p, 4); p += __shfl_xor(p, 8);
            if (l == 0) sc[h][RPC - 1] = p + mask[TCACHE - 1];
        }
    }
    __syncthreads();

    // ---- phase 2: chunk-local softmax stats + weights ----
    {
        float v[4];
        float m = -1e30f;
        #pragma unroll
        for (int j = 0; j < 4; ++j) {
            int r = l + 16 * j;
            v[j] = (r < RPC) ? sc[h][r] : -1e30f;
            m = fmaxf(m, v[j]);
        }
        #pragma unroll
        for (int d = 1; d <= 8; d <<= 1) m = fmaxf(m, __shfl_xor(m, d));
        float s = 0.f;
        #pragma unroll
        for (int j = 0; j < 4; ++j) {
            v[j] = __expf(v[j] - m);   // pad slots -> 0
            s += v[j];
        }
        #pragma unroll
        for (int d = 1; d <= 8; d <<= 1) s += __shfl_xor(s, d);
        __syncthreads();               // all reads of sc done before overwrite
        #pragma unroll
        for (int j = 0; j < 4; ++j) {
            int r = l + 16 * j;
            if (r < RPC) sc[h][r] = v[j];
        }
        if (l == 0) {
            m_ws[((size_t)b * NT + tc) * NHEAD + h] = m;
            s_ws[((size_t)b * NT + tc) * NHEAD + h] = s;
        }
    }
    __syncthreads();

    // ---- phase 3: V shift-copy + PV partial (chunk-local weights) ----
    float ax = 0.f, ay = 0.f, az = 0.f, aw = 0.f;
    {
        const float* src0 = vin + base + (size_t)(t0 + 1) * NSTATE + col;
        float* dst0 = vout + base + (size_t)t0 * NSTATE + col;
        #pragma unroll 4
        for (int r = 0; r < nrows; ++r) {
            f4 vv = __builtin_nontemporal_load((const f4*)(src0 + (size_t)r * NSTATE));
            __builtin_nontemporal_store(vv, (f4*)(dst0 + (size_t)r * NSTATE));
            const float w = sc[h][r];
            ax = fmaf(w, vv[0], ax); ay = fmaf(w, vv[1], ay);
            az = fmaf(w, vv[2], az); aw = fmaf(w, vv[3], aw);
        }
        if (tc == NT - 1) {            // row 447: already final in vout
            const f4 vv = *(const f4*)(vout + base + (size_t)(TCACHE-1) * NSTATE + col);
            const float w = sc[h][RPC - 1];
            ax = fmaf(w, vv[0], ax); ay = fmaf(w, vv[1], ay);
            az = fmaf(w, vv[2], az); aw = fmaf(w, vv[3], aw);
        }
    }
    *(float4*)(pvp + ((size_t)b * NT + tc) * NSTATE + col) =
        make_float4(ax, ay, az, aw);
}

// ---------------------------------------------------------------------------
// Combine NT chunk partials with online-softmax rescaling -> wv bf16 [128][1280]
// ---------------------------------------------------------------------------
__global__ void __launch_bounds__(256) combine_kernel(
    const float* __restrict__ pvp, const float* __restrict__ m_ws,
    const float* __restrict__ s_ws, u16* __restrict__ wvbf)
{
    const size_t idx = ((size_t)blockIdx.x * 256 + threadIdx.x) * 4;
    const int b = (int)(idx / NSTATE), col = (int)(idx % NSTATE);
    const int h = col >> 6;

    float m[NT], s[NT];
    float M = -1e30f;
    #pragma unroll
    for (int c = 0; c < NT; ++c) {
        m[c] = m_ws[((size_t)b * NT + c) * NHEAD + h];
        s[c] = s_ws[((size_t)b * NT + c) * NHEAD + h];
        M = fmaxf(M, m[c]);
    }
    float S = 0.f;
    float f[NT];
    #pragma unroll
    for (int c = 0; c < NT; ++c) { f[c] = __expf(m[c] - M); S += s[c] * f[c]; }
    const float inv = 1.0f / S;

    float4 acc = make_float4(0.f, 0.f, 0.f, 0.f);
    #pragma unroll
    for (int c = 0; c < NT; ++c) {
        const float w = f[c] * inv;
        float4 a = *(const float4*)(pvp + ((size_t)b * NT + c) * NSTATE + idx % NSTATE + (size_t)(idx / NSTATE) * 0);
        (void)a;
        a = *(const float4*)(pvp + ((size_t)b * NT + c) * NSTATE + col);
        acc.x = fmaf(w, a.x, acc.x); acc.y = fmaf(w, a.y, acc.y);
        acc.z = fmaf(w, a.z, acc.z); acc.w = fmaf(w, a.w, acc.w);
    }
    u16* o = wvbf + idx;
    o[0] = f2bf(acc.x); o[1] = f2bf(acc.y);
    o[2] = f2bf(acc.z); o[3] = f2bf(acc.w);
}

extern "C" void kernel_launch(void* const* d_in, const int* in_sizes, int n_in,
                              void* d_out, int out_size, void* d_ws, size_t ws_size,
                              hipStream_t stream)
{
    const float* x       = (const float*)d_in[0];
    const float* k_cache = (const float*)d_in[1];
    const float* v_cache = (const float*)d_in[2];
    const float* mask    = (const float*)d_in[3];
    const float* Wq      = (const float*)d_in[4];
    const float* bq      = (const float*)d_in[5];
    const float* Wk      = (const float*)d_in[6];
    const float* Wv      = (const float*)d_in[7];
    const float* bv      = (const float*)d_in[8];
    const float* Wo      = (const float*)d_in[9];
    const float* bo      = (const float*)d_in[10];

    float* out  = (float*)d_out;                                   // [128,1,1280]
    float* kout = out + (size_t)NBATCH * NSTATE;                   // [128,448,1280]
    float* vout = kout + (size_t)NBATCH * TCACHE * NSTATE;         // [128,448,1280]

    float* ws     = (float*)d_ws;
    float* q_ws   = ws;                                            // 163840 f
    float* pvp_ws = q_ws  + (size_t)NBATCH * NSTATE;               // 1310720 f
    float* m_ws   = pvp_ws + (size_t)NBATCH * NT * NSTATE;         // 20480 f
    float* s_ws   = m_ws  + (size_t)NBATCH * NT * NHEAD;           // 20480 f
    u16*   wvbf   = (u16*)(s_ws + (size_t)NBATCH * NT * NHEAD);    // 163840 u16

    // 1) q/k/v projection (MFMA, on-the-fly bf16): q -> ws; k,v -> row 447
    proj_mfma_kernel<<<dim3(20, 3), 512, 0, stream>>>(x, Wq, bq, Wk, Wv, bv,
                                                      q_ws, kout, vout);
    // 2) fused K/V streams with chunk-local softmax
    fused_stream_kernel<<<dim3(NT, NBATCH), 320, 0, stream>>>(
        k_cache, v_cache, q_ws, mask, kout, vout, pvp_ws, m_ws, s_ws);
    // 3) combine chunk partials (online-softmax rescale) -> wv bf16
    combine_kernel<<<dim3(160), 256, 0, stream>>>(pvp_ws, m_ws, s_ws, wvbf);
    // 4) output projection (MFMA) + bias
    outproj_mfma_kernel<<<dim3(20), 512, 0, stream>>>(wvbf, Wo, bo, out);
}

// Round 7
// 318.078 us; speedup vs baseline: 1.1337x; 1.1337x over previous
//
#include <hip/hip_runtime.h>
#include <cstddef>

#define NSTATE 1280
#define TCACHE 448
#define NBATCH 128
#define NHEAD  20
#define HDIM   64
#define NT     8
#define RPC    (TCACHE / NT)   // 56 rows per chunk

typedef float f4 __attribute__((ext_vector_type(4)));

// ---------------------------------------------------------------------------
// fp32 tiled GEMM: C[m][n] = (A[128][1280] @ B[kb:ke][1280] + bias) * scale
// BM=64, BN=32, BK=32, 256 threads, micro-tile 4x2. ldc parameterized so k/v
// projections write directly into row 447 of the output caches.
// ---------------------------------------------------------------------------
__device__ __forceinline__ void gemm_body(const float* __restrict__ A,
                                          const float* __restrict__ B,
                                          const float* __restrict__ bias,
                                          float* __restrict__ C, size_t ldc,
                                          int kb, int ke, float scale)
{
    __shared__ float As[32][64];   // [k][m]
    __shared__ float Bs[32][32];   // [k][n]
    const int tid = threadIdx.x;
    const int m0 = blockIdx.y * 64;
    const int n0 = blockIdx.x * 32;
    const int tr = tid >> 4;
    const int tc = tid & 15;
    float acc[4][2] = {{0.f,0.f},{0.f,0.f},{0.f,0.f},{0.f,0.f}};

    for (int k0 = kb; k0 < ke; k0 += 32) {
        #pragma unroll
        for (int j = 0; j < 2; ++j) {
            int chunk = tid * 2 + j;
            int row   = chunk >> 3;
            int kc    = (chunk & 7) << 2;
            float4 a = *(const float4*)(A + (size_t)(m0 + row) * NSTATE + k0 + kc);
            As[kc+0][row] = a.x; As[kc+1][row] = a.y;
            As[kc+2][row] = a.z; As[kc+3][row] = a.w;
        }
        {
            int row = tid >> 3;
            int nc  = (tid & 7) << 2;
            float4 b4 = *(const float4*)(B + (size_t)(k0 + row) * NSTATE + n0 + nc);
            *(float4*)&Bs[row][nc] = b4;
        }
        __syncthreads();
        #pragma unroll
        for (int kk = 0; kk < 32; ++kk) {
            float4 a = *(const float4*)&As[kk][tr << 2];
            float2 b = *(const float2*)&Bs[kk][tc << 1];
            acc[0][0] = fmaf(a.x, b.x, acc[0][0]); acc[0][1] = fmaf(a.x, b.y, acc[0][1]);
            acc[1][0] = fmaf(a.y, b.x, acc[1][0]); acc[1][1] = fmaf(a.y, b.y, acc[1][1]);
            acc[2][0] = fmaf(a.z, b.x, acc[2][0]); acc[2][1] = fmaf(a.z, b.y, acc[2][1]);
            acc[3][0] = fmaf(a.w, b.x, acc[3][0]); acc[3][1] = fmaf(a.w, b.y, acc[3][1]);
        }
        __syncthreads();
    }
    const int n = n0 + (tc << 1);
    const float b0 = bias ? bias[n]   : 0.f;
    const float b1 = bias ? bias[n+1] : 0.f;
    #pragma unroll
    for (int i = 0; i < 4; ++i) {
        size_t m = (size_t)(m0 + (tr << 2) + i);
        C[m * ldc + n]     = (acc[i][0] + b0) * scale;
        C[m * ldc + n + 1] = (acc[i][1] + b1) * scale;
    }
}

// q/k/v projection, direct write. grid (40, 2, 3): z=0 q (scaled, ->ws),
// z=1 k -> row 447 kout (no bias), z=2 v -> row 447 vout.
__global__ void __launch_bounds__(256) proj_qkv_kernel(
    const float* __restrict__ x,
    const float* __restrict__ Wq, const float* __restrict__ bq,
    const float* __restrict__ Wk,
    const float* __restrict__ Wv, const float* __restrict__ bv,
    float* __restrict__ q_ws, float* __restrict__ kout, float* __restrict__ vout)
{
    const int z = blockIdx.z;
    if (z == 0) {
        gemm_body(x, Wq, bq, q_ws, NSTATE, 0, NSTATE, 0.125f);   // both scales folded
    } else if (z == 1) {
        gemm_body(x, Wk, nullptr, kout + (size_t)(TCACHE-1) * NSTATE,
                  (size_t)TCACHE * NSTATE, 0, NSTATE, 1.0f);
    } else {
        gemm_body(x, Wv, bv, vout + (size_t)(TCACHE-1) * NSTATE,
                  (size_t)TCACHE * NSTATE, 0, NSTATE, 1.0f);
    }
}

// ---------------------------------------------------------------------------
// Fused stream kernel, SINGLE PASS with online softmax:
// per (chunk, batch) block, per row: load K row + V row (2 loads in flight),
// store both shifted rows, online-update (m, s, acc) per 16-lane head group.
// No LDS, no barriers. Outputs pvp [b][tc][1280], m/s stats [b][tc][20]
// with identical semantics to the two-pass version (combine unchanged).
// grid (NT, 128), 320 threads: thread = one float4 slot of a row, h = tid>>4.
// ---------------------------------------------------------------------------
__global__ void __launch_bounds__(320) fused_stream_kernel(
    const float* __restrict__ kin, const float* __restrict__ vin,
    const float* __restrict__ q_ws, const float* __restrict__ mask,
    float* __restrict__ kout, float* __restrict__ vout,
    float* __restrict__ pvp, float* __restrict__ m_ws, float* __restrict__ s_ws)
{
    const int tc = blockIdx.x, b = blockIdx.y;
    const int tid = threadIdx.x;
    const int h = tid >> 4, l = tid & 15;
    const int col = tid << 2;
    const size_t base = (size_t)b * TCACHE * NSTATE;
    const int t0 = tc * RPC;
    const int nrows = (tc == NT - 1) ? RPC - 1 : RPC;

    const float4 q4 = *(const float4*)(q_ws + (size_t)b * NSTATE + col);
    const float* ksrc = kin + base + (size_t)(t0 + 1) * NSTATE + col;
    const float* vsrc = vin + base + (size_t)(t0 + 1) * NSTATE + col;
    float* kdst = kout + base + (size_t)t0 * NSTATE + col;
    float* vdst = vout + base + (size_t)t0 * NSTATE + col;

    float m = -1e30f, s = 0.f;
    float ax = 0.f, ay = 0.f, az = 0.f, aw = 0.f;

    #pragma unroll 4
    for (int r = 0; r < nrows; ++r) {
        f4 kv = __builtin_nontemporal_load((const f4*)(ksrc + (size_t)r * NSTATE));
        f4 vv = __builtin_nontemporal_load((const f4*)(vsrc + (size_t)r * NSTATE));
        __builtin_nontemporal_store(kv, (f4*)(kdst + (size_t)r * NSTATE));
        __builtin_nontemporal_store(vv, (f4*)(vdst + (size_t)r * NSTATE));
        float p = kv[0]*q4.x + kv[1]*q4.y + kv[2]*q4.z + kv[3]*q4.w;
        p += __shfl_xor(p, 1); p += __shfl_xor(p, 2);
        p += __shfl_xor(p, 4); p += __shfl_xor(p, 8);
        p += mask[t0 + r];
        const float mn = fmaxf(m, p);
        const float c  = __expf(m - mn);
        const float w  = __expf(p - mn);
        s = fmaf(s, c, w);
        ax = fmaf(ax, c, w * vv[0]);
        ay = fmaf(ay, c, w * vv[1]);
        az = fmaf(az, c, w * vv[2]);
        aw = fmaf(aw, c, w * vv[3]);
        m = mn;
    }
    if (tc == NT - 1) {                // row 447: already final in kout/vout
        const f4 kv = *(const f4*)(kout + base + (size_t)(TCACHE-1) * NSTATE + col);
        const f4 vv = *(const f4*)(vout + base + (size_t)(TCACHE-1) * NSTATE + col);
        float p = kv[0]*q4.x + kv[1]*q4.y + kv[2]*q4.z + kv[3]*q4.w;
        p += __shfl_xor(p, 1); p += __shfl_xor(p, 2);
        p += __shfl_xor(p, 4); p += __shfl_xor(p, 8);
        p += mask[TCACHE - 1];
        const float mn = fmaxf(m, p);
        const float c  = __expf(m - mn);
        const float w  = __expf(p - mn);
        s = fmaf(s, c, w);
        ax = fmaf(ax, c, w * vv[0]);
        ay = fmaf(ay, c, w * vv[1]);
        az = fmaf(az, c, w * vv[2]);
        aw = fmaf(aw, c, w * vv[3]);
        m = mn;
    }

    if (l == 0) {
        m_ws[((size_t)b * NT + tc) * NHEAD + h] = m;
        s_ws[((size_t)b * NT + tc) * NHEAD + h] = s;
    }
    *(float4*)(pvp + ((size_t)b * NT + tc) * NSTATE + col) =
        make_float4(ax, ay, az, aw);
}

// ---------------------------------------------------------------------------
// Combine the NT chunk partials with online-softmax rescaling -> wv [128][1280]
// ---------------------------------------------------------------------------
__global__ void __launch_bounds__(256) combine_kernel(
    const float* __restrict__ pvp, const float* __restrict__ m_ws,
    const float* __restrict__ s_ws, float* __restrict__ wv_ws)
{
    const size_t idx = ((size_t)blockIdx.x * 256 + threadIdx.x) * 4;
    const int b = (int)(idx / NSTATE), col = (int)(idx % NSTATE);
    const int h = col >> 6;

    float m[NT], s[NT];
    float M = -1e30f;
    #pragma unroll
    for (int c = 0; c < NT; ++c) {
        m[c] = m_ws[((size_t)b * NT + c) * NHEAD + h];
        s[c] = s_ws[((size_t)b * NT + c) * NHEAD + h];
        M = fmaxf(M, m[c]);
    }
    float S = 0.f;
    float f[NT];
    #pragma unroll
    for (int c = 0; c < NT; ++c) { f[c] = __expf(m[c] - M); S += s[c] * f[c]; }
    const float inv = 1.0f / S;

    float4 acc = make_float4(0.f, 0.f, 0.f, 0.f);
    #pragma unroll
    for (int c = 0; c < NT; ++c) {
        const float w = f[c] * inv;
        float4 a = *(const float4*)(pvp + ((size_t)b * NT + c) * NSTATE + col);
        acc.x = fmaf(w, a.x, acc.x); acc.y = fmaf(w, a.y, acc.y);
        acc.z = fmaf(w, a.z, acc.z); acc.w = fmaf(w, a.w, acc.w);
    }
    *(float4*)(wv_ws + idx) = acc;
}

// output projection partials. grid (40, 2, 4): z = K-split (4 x 320).
__global__ void __launch_bounds__(256) outproj_kernel(
    const float* __restrict__ wv, const float* __restrict__ Wo,
    float* __restrict__ po)
{
    const int sp = blockIdx.z;
    gemm_body(wv, Wo, nullptr, po + (size_t)sp * NBATCH * NSTATE,
              NSTATE, sp * 320, sp * 320 + 320, 1.0f);
}

__global__ void __launch_bounds__(256) out_reduce_kernel(
    const float* __restrict__ po, const float* __restrict__ bo,
    float* __restrict__ out)
{
    const size_t idx = ((size_t)blockIdx.x * 256 + threadIdx.x) * 4;
    const int col = (int)(idx % NSTATE);
    float4 s = *(const float4*)(bo + col);
    #pragma unroll
    for (int c = 0; c < 4; ++c) {
        float4 a = *(const float4*)(po + (size_t)c * NBATCH * NSTATE + idx);
        s.x += a.x; s.y += a.y; s.z += a.z; s.w += a.w;
    }
    *(float4*)(out + idx) = s;
}

extern "C" void kernel_launch(void* const* d_in, const int* in_sizes, int n_in,
                              void* d_out, int out_size, void* d_ws, size_t ws_size,
                              hipStream_t stream)
{
    const float* x       = (const float*)d_in[0];
    const float* k_cache = (const float*)d_in[1];
    const float* v_cache = (const float*)d_in[2];
    const float* mask    = (const float*)d_in[3];
    const float* Wq      = (const float*)d_in[4];
    const float* bq      = (const float*)d_in[5];
    const float* Wk      = (const float*)d_in[6];
    const float* Wv      = (const float*)d_in[7];
    const float* bv      = (const float*)d_in[8];
    const float* Wo      = (const float*)d_in[9];
    const float* bo      = (const float*)d_in[10];

    float* out  = (float*)d_out;                                   // [128,1,1280]
    float* kout = out + (size_t)NBATCH * NSTATE;                   // [128,448,1280]
    float* vout = kout + (size_t)NBATCH * TCACHE * NSTATE;         // [128,448,1280]

    float* ws     = (float*)d_ws;
    float* q_ws   = ws;                                            // 163840
    float* pvp_ws = q_ws  + (size_t)NBATCH * NSTATE;               // 1310720
    float* m_ws   = pvp_ws + (size_t)NBATCH * NT * NSTATE;         // 20480
    float* s_ws   = m_ws  + (size_t)NBATCH * NT * NHEAD;           // 20480
    float* wv_ws  = s_ws  + (size_t)NBATCH * NT * NHEAD;           // 163840
    float* po_ws  = wv_ws + (size_t)NBATCH * NSTATE;               // 655360

    // 1) q/k/v projection: q -> ws (pre-scaled); k,v -> row 447 of out caches
    proj_qkv_kernel<<<dim3(40, 2, 3), 256, 0, stream>>>(x, Wq, bq, Wk, Wv, bv,
                                                        q_ws, kout, vout);
    // 2) fused K/V single-pass stream with online softmax
    fused_stream_kernel<<<dim3(NT, NBATCH), 320, 0, stream>>>(
        k_cache, v_cache, q_ws, mask, kout, vout, pvp_ws, m_ws, s_ws);
    // 3) combine chunk partials (online-softmax rescale)
    combine_kernel<<<dim3(160), 256, 0, stream>>>(pvp_ws, m_ws, s_ws, wv_ws);
    // 4) output projection (split-K) + reduce with bias
    outproj_kernel<<<dim3(40, 2, 4), 256, 0, stream>>>(wv_ws, Wo, po_ws);
    out_reduce_kernel<<<dim3(160), 256, 0, stream>>>(po_ws, bo, out);
}

// Round 8
// 304.035 us; speedup vs baseline: 1.1860x; 1.0462x over previous
//
#include <hip/hip_runtime.h>
#include <cstddef>

#define NSTATE 1280
#define TCACHE 448
#define NBATCH 128
#define NHEAD  20
#define HDIM   64
#define NT     8
#define RPC    (TCACHE / NT)   // 56 rows per chunk

typedef float f4 __attribute__((ext_vector_type(4)));

// ---------------------------------------------------------------------------
// fp32 tiled GEMM: C[m][n] = (A[128][1280] @ B[kb:ke][1280] + bias) * scale
// BM=64, BN=32, BK=32, 256 threads, micro-tile 4x2. ldc parameterized so k/v
// projections write directly into row 447 of the output caches.
// ---------------------------------------------------------------------------
__device__ __forceinline__ void gemm_body(const float* __restrict__ A,
                                          const float* __restrict__ B,
                                          const float* __restrict__ bias,
                                          float* __restrict__ C, size_t ldc,
                                          int kb, int ke, float scale)
{
    __shared__ float As[32][64];   // [k][m]
    __shared__ float Bs[32][32];   // [k][n]
    const int tid = threadIdx.x;
    const int m0 = blockIdx.y * 64;
    const int n0 = blockIdx.x * 32;
    const int tr = tid >> 4;
    const int tc = tid & 15;
    float acc[4][2] = {{0.f,0.f},{0.f,0.f},{0.f,0.f},{0.f,0.f}};

    for (int k0 = kb; k0 < ke; k0 += 32) {
        #pragma unroll
        for (int j = 0; j < 2; ++j) {
            int chunk = tid * 2 + j;
            int row   = chunk >> 3;
            int kc    = (chunk & 7) << 2;
            float4 a = *(const float4*)(A + (size_t)(m0 + row) * NSTATE + k0 + kc);
            As[kc+0][row] = a.x; As[kc+1][row] = a.y;
            As[kc+2][row] = a.z; As[kc+3][row] = a.w;
        }
        {
            int row = tid >> 3;
            int nc  = (tid & 7) << 2;
            float4 b4 = *(const float4*)(B + (size_t)(k0 + row) * NSTATE + n0 + nc);
            *(float4*)&Bs[row][nc] = b4;
        }
        __syncthreads();
        #pragma unroll
        for (int kk = 0; kk < 32; ++kk) {
            float4 a = *(const float4*)&As[kk][tr << 2];
            float2 b = *(const float2*)&Bs[kk][tc << 1];
            acc[0][0] = fmaf(a.x, b.x, acc[0][0]); acc[0][1] = fmaf(a.x, b.y, acc[0][1]);
            acc[1][0] = fmaf(a.y, b.x, acc[1][0]); acc[1][1] = fmaf(a.y, b.y, acc[1][1]);
            acc[2][0] = fmaf(a.z, b.x, acc[2][0]); acc[2][1] = fmaf(a.z, b.y, acc[2][1]);
            acc[3][0] = fmaf(a.w, b.x, acc[3][0]); acc[3][1] = fmaf(a.w, b.y, acc[3][1]);
        }
        __syncthreads();
    }
    const int n = n0 + (tc << 1);
    const float b0 = bias ? bias[n]   : 0.f;
    const float b1 = bias ? bias[n+1] : 0.f;
    #pragma unroll
    for (int i = 0; i < 4; ++i) {
        size_t m = (size_t)(m0 + (tr << 2) + i);
        C[m * ldc + n]     = (acc[i][0] + b0) * scale;
        C[m * ldc + n + 1] = (acc[i][1] + b1) * scale;
    }
}

// q/k/v projection, direct write. grid (40, 2, 3): z=0 q (scaled, ->ws),
// z=1 k -> row 447 kout (no bias), z=2 v -> row 447 vout.
__global__ void __launch_bounds__(256) proj_qkv_kernel(
    const float* __restrict__ x,
    const float* __restrict__ Wq, const float* __restrict__ bq,
    const float* __restrict__ Wk,
    const float* __restrict__ Wv, const float* __restrict__ bv,
    float* __restrict__ q_ws, float* __restrict__ kout, float* __restrict__ vout)
{
    const int z = blockIdx.z;
    if (z == 0) {
        gemm_body(x, Wq, bq, q_ws, NSTATE, 0, NSTATE, 0.125f);   // both scales folded
    } else if (z == 1) {
        gemm_body(x, Wk, nullptr, kout + (size_t)(TCACHE-1) * NSTATE,
                  (size_t)TCACHE * NSTATE, 0, NSTATE, 1.0f);
    } else {
        gemm_body(x, Wv, bv, vout + (size_t)(TCACHE-1) * NSTATE,
                  (size_t)TCACHE * NSTATE, 0, NSTATE, 1.0f);
    }
}

// ---------------------------------------------------------------------------
// Fused stream kernel (two-pass, chunk-local softmax) with EXPLICIT 8-DEEP
// LOAD BATCHING: each phase issues 8 nt loads into registers, then 8 nt
// stores, then all compute — keeps 128 B/thread of reads in flight.
// grid (NT, 128), 320 threads: thread = one float4 slot of a row, h = tid>>4.
// ---------------------------------------------------------------------------
__global__ void __launch_bounds__(320) fused_stream_kernel(
    const float* __restrict__ kin, const float* __restrict__ vin,
    const float* __restrict__ q_ws, const float* __restrict__ mask,
    float* __restrict__ kout, float* __restrict__ vout,
    float* __restrict__ pvp, float* __restrict__ m_ws, float* __restrict__ s_ws)
{
    const int tc = blockIdx.x, b = blockIdx.y;
    const int tid = threadIdx.x;
    const int h = tid >> 4, l = tid & 15;
    const int col = tid << 2;
    const size_t base = (size_t)b * TCACHE * NSTATE;
    const int t0 = tc * RPC;
    const int nrows = (tc == NT - 1) ? RPC - 1 : RPC;

    __shared__ float sc[NHEAD][RPC];   // raw scores, then weights

    const float4 q4 = *(const float4*)(q_ws + (size_t)b * NSTATE + col);
    const float* ksrc = kin + base + (size_t)(t0 + 1) * NSTATE + col;
    const float* vsrc = vin + base + (size_t)(t0 + 1) * NSTATE + col;
    float* kdst = kout + base + (size_t)t0 * NSTATE + col;
    float* vdst = vout + base + (size_t)t0 * NSTATE + col;

    // ---- phase 1: K shift-copy + scores (8-deep batches) ----
    {
        int r = 0;
        for (; r + 8 <= nrows; r += 8) {
            f4 kb[8];
            #pragma unroll
            for (int j = 0; j < 8; ++j)
                kb[j] = __builtin_nontemporal_load((const f4*)(ksrc + (size_t)(r + j) * NSTATE));
            #pragma unroll
            for (int j = 0; j < 8; ++j)
                __builtin_nontemporal_store(kb[j], (f4*)(kdst + (size_t)(r + j) * NSTATE));
            #pragma unroll
            for (int j = 0; j < 8; ++j) {
                float p = kb[j][0]*q4.x + kb[j][1]*q4.y + kb[j][2]*q4.z + kb[j][3]*q4.w;
                p += __shfl_xor(p, 1); p += __shfl_xor(p, 2);
                p += __shfl_xor(p, 4); p += __shfl_xor(p, 8);
                if (l == 0) sc[h][r + j] = p + mask[t0 + r + j];
            }
        }
        for (; r < nrows; ++r) {
            f4 kv = __builtin_nontemporal_load((const f4*)(ksrc + (size_t)r * NSTATE));
            __builtin_nontemporal_store(kv, (f4*)(kdst + (size_t)r * NSTATE));
            float p = kv[0]*q4.x + kv[1]*q4.y + kv[2]*q4.z + kv[3]*q4.w;
            p += __shfl_xor(p, 1); p += __shfl_xor(p, 2);
            p += __shfl_xor(p, 4); p += __shfl_xor(p, 8);
            if (l == 0) sc[h][r] = p + mask[t0 + r];
        }
        if (tc == NT - 1) {            // row 447: already final in kout
            const f4 kv = *(const f4*)(kout + base + (size_t)(TCACHE-1) * NSTATE + col);
            float p = kv[0]*q4.x + kv[1]*q4.y + kv[2]*q4.z + kv[3]*q4.w;
            p += __shfl_xor(p, 1); p += __shfl_xor(p, 2);
            p += __shfl_xor(p, 4); p += __shfl_xor(p, 8);
            if (l == 0) sc[h][RPC - 1] = p + mask[TCACHE - 1];
        }
    }
    __syncthreads();

    // ---- phase 2: chunk-local softmax stats + weights ----
    {
        float v[4];
        float m = -1e30f;
        #pragma unroll
        for (int j = 0; j < 4; ++j) {
            int r = l + 16 * j;
            v[j] = (r < RPC) ? sc[h][r] : -1e30f;
            m = fmaxf(m, v[j]);
        }
        #pragma unroll
        for (int d = 1; d <= 8; d <<= 1) m = fmaxf(m, __shfl_xor(m, d));
        float s = 0.f;
        #pragma unroll
        for (int j = 0; j < 4; ++j) {
            v[j] = __expf(v[j] - m);   // pad slots -> 0
            s += v[j];
        }
        #pragma unroll
        for (int d = 1; d <= 8; d <<= 1) s += __shfl_xor(s, d);
        __syncthreads();               // all reads of sc done before overwrite
        #pragma unroll
        for (int j = 0; j < 4; ++j) {
            int r = l + 16 * j;
            if (r < RPC) sc[h][r] = v[j];
        }
        if (l == 0) {
            m_ws[((size_t)b * NT + tc) * NHEAD + h] = m;
            s_ws[((size_t)b * NT + tc) * NHEAD + h] = s;
        }
    }
    __syncthreads();

    // ---- phase 3: V shift-copy + PV partial (8-deep batches) ----
    float ax = 0.f, ay = 0.f, az = 0.f, aw = 0.f;
    {
        int r = 0;
        for (; r + 8 <= nrows; r += 8) {
            f4 vb[8];
            #pragma unroll
            for (int j = 0; j < 8; ++j)
                vb[j] = __builtin_nontemporal_load((const f4*)(vsrc + (size_t)(r + j) * NSTATE));
            #pragma unroll
            for (int j = 0; j < 8; ++j)
                __builtin_nontemporal_store(vb[j], (f4*)(vdst + (size_t)(r + j) * NSTATE));
            #pragma unroll
            for (int j = 0; j < 8; ++j) {
                const float w = sc[h][r + j];
                ax = fmaf(w, vb[j][0], ax); ay = fmaf(w, vb[j][1], ay);
                az = fmaf(w, vb[j][2], az); aw = fmaf(w, vb[j][3], aw);
            }
        }
        for (; r < nrows; ++r) {
            f4 vv = __builtin_nontemporal_load((const f4*)(vsrc + (size_t)r * NSTATE));
            __builtin_nontemporal_store(vv, (f4*)(vdst + (size_t)r * NSTATE));
            const float w = sc[h][r];
            ax = fmaf(w, vv[0], ax); ay = fmaf(w, vv[1], ay);
            az = fmaf(w, vv[2], az); aw = fmaf(w, vv[3], aw);
        }
        if (tc == NT - 1) {            // row 447: already final in vout
            const f4 vv = *(const f4*)(vout + base + (size_t)(TCACHE-1) * NSTATE + col);
            const float w = sc[h][RPC - 1];
            ax = fmaf(w, vv[0], ax); ay = fmaf(w, vv[1], ay);
            az = fmaf(w, vv[2], az); aw = fmaf(w, vv[3], aw);
        }
    }
    *(float4*)(pvp + ((size_t)b * NT + tc) * NSTATE + col) =
        make_float4(ax, ay, az, aw);
}

// ---------------------------------------------------------------------------
// Combine the NT chunk partials with online-softmax rescaling -> wv [128][1280]
// ---------------------------------------------------------------------------
__global__ void __launch_bounds__(256) combine_kernel(
    const float* __restrict__ pvp, const float* __restrict__ m_ws,
    const float* __restrict__ s_ws, float* __restrict__ wv_ws)
{
    const size_t idx = ((size_t)blockIdx.x * 256 + threadIdx.x) * 4;
    const int b = (int)(idx / NSTATE), col = (int)(idx % NSTATE);
    const int h = col >> 6;

    float m[NT], s[NT];
    float M = -1e30f;
    #pragma unroll
    for (int c = 0; c < NT; ++c) {
        m[c] = m_ws[((size_t)b * NT + c) * NHEAD + h];
        s[c] = s_ws[((size_t)b * NT + c) * NHEAD + h];
        M = fmaxf(M, m[c]);
    }
    float S = 0.f;
    float f[NT];
    #pragma unroll
    for (int c = 0; c < NT; ++c) { f[c] = __expf(m[c] - M); S += s[c] * f[c]; }
    const float inv = 1.0f / S;

    float4 acc = make_float4(0.f, 0.f, 0.f, 0.f);
    #pragma unroll
    for (int c = 0; c < NT; ++c) {
        const float w = f[c] * inv;
        float4 a = *(const float4*)(pvp + ((size_t)b * NT + c) * NSTATE + col);
        acc.x = fmaf(w, a.x, acc.x); acc.y = fmaf(w, a.y, acc.y);
        acc.z = fmaf(w, a.z, acc.z); acc.w = fmaf(w, a.w, acc.w);
    }
    *(float4*)(wv_ws + idx) = acc;
}

// output projection partials. grid (40, 2, 4): z = K-split (4 x 320).
__global__ void __launch_bounds__(256) outproj_kernel(
    const float* __restrict__ wv, const float* __restrict__ Wo,
    float* __restrict__ po)
{
    const int sp = blockIdx.z;
    gemm_body(wv, Wo, nullptr, po + (size_t)sp * NBATCH * NSTATE,
              NSTATE, sp * 320, sp * 320 + 320, 1.0f);
}

__global__ void __launch_bounds__(256) out_reduce_kernel(
    const float* __restrict__ po, const float* __restrict__ bo,
    float* __restrict__ out)
{
    const size_t idx = ((size_t)blockIdx.x * 256 + threadIdx.x) * 4;
    const int col = (int)(idx % NSTATE);
    float4 s = *(const float4*)(bo + col);
    #pragma unroll
    for (int c = 0; c < 4; ++c) {
        float4 a = *(const float4*)(po + (size_t)c * NBATCH * NSTATE + idx);
        s.x += a.x; s.y += a.y; s.z += a.z; s.w += a.w;
    }
    *(float4*)(out + idx) = s;
}

extern "C" void kernel_launch(void* const* d_in, const int* in_sizes, int n_in,
                              void* d_out, int out_size, void* d_ws, size_t ws_size,
                              hipStream_t stream)
{
    const float* x       = (const float*)d_in[0];
    const float* k_cache = (const float*)d_in[1];
    const float* v_cache = (const float*)d_in[2];
    const float* mask    = (const float*)d_in[3];
    const float* Wq      = (const float*)d_in[4];
    const float* bq      = (const float*)d_in[5];
    const float* Wk      = (const float*)d_in[6];
    const float* Wv      = (const float*)d_in[7];
    const float* bv      = (const float*)d_in[8];
    const float* Wo      = (const float*)d_in[9];
    const float* bo      = (const float*)d_in[10];

    float* out  = (float*)d_out;                                   // [128,1,1280]
    float* kout = out + (size_t)NBATCH * NSTATE;                   // [128,448,1280]
    float* vout = kout + (size_t)NBATCH * TCACHE * NSTATE;         // [128,448,1280]

    float* ws     = (float*)d_ws;
    float* q_ws   = ws;                                            // 163840
    float* pvp_ws = q_ws  + (size_t)NBATCH * NSTATE;               // 1310720
    float* m_ws   = pvp_ws + (size_t)NBATCH * NT * NSTATE;         // 20480
    float* s_ws   = m_ws  + (size_t)NBATCH * NT * NHEAD;           // 20480
    float* wv_ws  = s_ws  + (size_t)NBATCH * NT * NHEAD;           // 163840
    float* po_ws  = wv_ws + (size_t)NBATCH * NSTATE;               // 655360

    // 1) q/k/v projection: q -> ws (pre-scaled); k,v -> row 447 of out caches
    proj_qkv_kernel<<<dim3(40, 2, 3), 256, 0, stream>>>(x, Wq, bq, Wk, Wv, bv,
                                                        q_ws, kout, vout);
    // 2) fused K/V two-pass stream, 8-deep load batching
    fused_stream_kernel<<<dim3(NT, NBATCH), 320, 0, stream>>>(
        k_cache, v_cache, q_ws, mask, kout, vout, pvp_ws, m_ws, s_ws);
    // 3) combine chunk partials (online-softmax rescale)
    combine_kernel<<<dim3(160), 256, 0, stream>>>(pvp_ws, m_ws, s_ws, wv_ws);
    // 4) output projection (split-K) + reduce with bias
    outproj_kernel<<<dim3(40, 2, 4), 256, 0, stream>>>(wv_ws, Wo, po_ws);
    out_reduce_kernel<<<dim3(160), 256, 0, stream>>>(po_ws, bo, out);
}

// Round 9
// 266.445 us; speedup vs baseline: 1.3534x; 1.1411x over previous
//
#include <hip/hip_runtime.h>
#include <cstddef>

#define NSTATE 1280
#define TCACHE 448
#define NBATCH 128
#define NHEAD  20
#define HDIM   64
#define NT     8
#define RPC    (TCACHE / NT)   // 56 rows per chunk
#define KSPLIT 4
#define KRANGE (NSTATE / KSPLIT)   // 320

typedef float f4 __attribute__((ext_vector_type(4)));
typedef float f32x4 __attribute__((ext_vector_type(4)));
typedef short bf16x8 __attribute__((ext_vector_type(8)));
typedef unsigned short u16;
typedef unsigned short u16x8 __attribute__((ext_vector_type(8)));

__device__ __forceinline__ u16 f2bf(float f) {
    unsigned u = __builtin_bit_cast(unsigned, f);
    u += 0x7fff + ((u >> 16) & 1);          // RTN-even (finite inputs)
    return (u16)(u >> 16);
}

// ---------------------------------------------------------------------------
// LDS-staged bf16 MFMA GEMM partial:
//   P[128][n0:n0+64] = A_f32[128][kb:kb+320] @ W_f32[kb:kb+320][n0:n0+64]
// 256 thr (4 waves). A_s[m][k] bf16 (row pad +8), B_s[n][k] bf16 transposed in
// LDS so both MFMA fragments are k-contiguous ds_read_b128 (2-way bank alias
// only). Wave w owns n-slice w*16; 8 m-frags of 16; fp32 accum.
// A-frag: row=lane&15, k=(lane>>4)*8+j. D: col=lane&15, row=(lane>>4)*4+reg.
// ---------------------------------------------------------------------------
__device__ __forceinline__ void mfma_partial_body(
    const float* __restrict__ A, const float* __restrict__ W,
    float* __restrict__ P)
{
    __shared__ u16 As[128][40];
    __shared__ u16 Bs[64][40];
    const int tid = threadIdx.x;
    const int n0 = blockIdx.x * 64;
    const int kb = blockIdx.y * KRANGE;
    const int w = tid >> 6, l = tid & 63;
    const int la = l & 15, kg = l >> 4;
    const int arow = tid >> 1, akh = (tid & 1) << 4;   // A stage: row, k-half
    const int bkr = tid >> 3, bnc = (tid & 7) << 3;    // B stage: k-row, n-chunk
    f32x4 acc[8] = {};

    for (int ks = 0; ks < KRANGE; ks += 32) {
        // stage A tile: x[arow][kb+ks+akh .. +16] -> As[arow][akh .. +16]
        {
            const float* src = A + (size_t)arow * NSTATE + kb + ks + akh;
            float4 v0 = *(const float4*)(src);
            float4 v1 = *(const float4*)(src + 4);
            float4 v2 = *(const float4*)(src + 8);
            float4 v3 = *(const float4*)(src + 12);
            u16x8 w0, w1;
            w0[0]=f2bf(v0.x); w0[1]=f2bf(v0.y); w0[2]=f2bf(v0.z); w0[3]=f2bf(v0.w);
            w0[4]=f2bf(v1.x); w0[5]=f2bf(v1.y); w0[6]=f2bf(v1.z); w0[7]=f2bf(v1.w);
            w1[0]=f2bf(v2.x); w1[1]=f2bf(v2.y); w1[2]=f2bf(v2.z); w1[3]=f2bf(v2.w);
            w1[4]=f2bf(v3.x); w1[5]=f2bf(v3.y); w1[6]=f2bf(v3.z); w1[7]=f2bf(v3.w);
            *(u16x8*)&As[arow][akh]     = w0;
            *(u16x8*)&As[arow][akh + 8] = w1;
        }
        // stage B tile transposed: W[kb+ks+bkr][n0+bnc .. +8] -> Bs[bnc+j][bkr]
        {
            const float* src = W + (size_t)(kb + ks + bkr) * NSTATE + n0 + bnc;
            float4 b0 = *(const float4*)(src);
            float4 b1 = *(const float4*)(src + 4);
            Bs[bnc + 0][bkr] = f2bf(b0.x); Bs[bnc + 1][bkr] = f2bf(b0.y);
            Bs[bnc + 2][bkr] = f2bf(b0.z); Bs[bnc + 3][bkr] = f2bf(b0.w);
            Bs[bnc + 4][bkr] = f2bf(b1.x); Bs[bnc + 5][bkr] = f2bf(b1.y);
            Bs[bnc + 6][bkr] = f2bf(b1.z); Bs[bnc + 7][bkr] = f2bf(b1.w);
        }
        __syncthreads();
        const bf16x8 bf = *(const bf16x8*)&Bs[w * 16 + la][kg * 8];
        #pragma unroll
        for (int mf = 0; mf < 8; ++mf) {
            bf16x8 af = *(const bf16x8*)&As[mf * 16 + la][kg * 8];
            acc[mf] = __builtin_amdgcn_mfma_f32_16x16x32_bf16(af, bf, acc[mf], 0, 0, 0);
        }
        __syncthreads();
    }
    const int col = n0 + w * 16 + la;
    #pragma unroll
    for (int mf = 0; mf < 8; ++mf)
        #pragma unroll
        for (int j = 0; j < 4; ++j)
            P[(size_t)(mf * 16 + kg * 4 + j) * NSTATE + col] = acc[mf][j];
}

// q/k/v projection partials. grid (20, 4, 3): x=n-tile, y=K-split, z=mat.
__global__ void __launch_bounds__(256) proj_mfma_kernel(
    const float* __restrict__ x,
    const float* __restrict__ Wq, const float* __restrict__ Wk,
    const float* __restrict__ Wv, float* __restrict__ pp)
{
    const int z = blockIdx.z;
    const float* W = (z == 0) ? Wq : (z == 1) ? Wk : Wv;
    mfma_partial_body(x, W,
        pp + (size_t)(z * KSPLIT + blockIdx.y) * NBATCH * NSTATE);
}

// combine proj split-K partials + bias; scatter q->ws (scaled), k/v -> row 447.
__global__ void __launch_bounds__(256) proj_reduce_kernel(
    const float* __restrict__ pp, const float* __restrict__ bq,
    const float* __restrict__ bv, float* __restrict__ q_ws,
    float* __restrict__ kout, float* __restrict__ vout)
{
    const int mat = blockIdx.y;
    const size_t idx = ((size_t)blockIdx.x * 256 + threadIdx.x) * 4;
    const int b = (int)(idx / NSTATE), col = (int)(idx % NSTATE);
    float4 v = make_float4(0.f, 0.f, 0.f, 0.f);
    #pragma unroll
    for (int c = 0; c < KSPLIT; ++c) {
        float4 a = *(const float4*)(pp + (size_t)(mat * KSPLIT + c) * NBATCH * NSTATE + idx);
        v.x += a.x; v.y += a.y; v.z += a.z; v.w += a.w;
    }
    if (mat == 0) {
        float4 bb = *(const float4*)(bq + col);
        v.x = (v.x + bb.x) * 0.125f; v.y = (v.y + bb.y) * 0.125f;
        v.z = (v.z + bb.z) * 0.125f; v.w = (v.w + bb.w) * 0.125f;
        *(float4*)(q_ws + idx) = v;
    } else if (mat == 1) {
        *(float4*)(kout + ((size_t)b * TCACHE + TCACHE - 1) * NSTATE + col) = v;
    } else {
        float4 bb = *(const float4*)(bv + col);
        v.x += bb.x; v.y += bb.y; v.z += bb.z; v.w += bb.w;
        *(float4*)(vout + ((size_t)b * TCACHE + TCACHE - 1) * NSTATE + col) = v;
    }
}

// ---------------------------------------------------------------------------
// Fused stream kernel (two-pass, chunk-local softmax) with 8-deep batching.
// grid (NT, 128), 320 threads: thread = one float4 slot of a row, h = tid>>4.
// ---------------------------------------------------------------------------
__global__ void __launch_bounds__(320) fused_stream_kernel(
    const float* __restrict__ kin, const float* __restrict__ vin,
    const float* __restrict__ q_ws, const float* __restrict__ mask,
    float* __restrict__ kout, float* __restrict__ vout,
    float* __restrict__ pvp, float* __restrict__ m_ws, float* __restrict__ s_ws)
{
    const int tc = blockIdx.x, b = blockIdx.y;
    const int tid = threadIdx.x;
    const int h = tid >> 4, l = tid & 15;
    const int col = tid << 2;
    const size_t base = (size_t)b * TCACHE * NSTATE;
    const int t0 = tc * RPC;
    const int nrows = (tc == NT - 1) ? RPC - 1 : RPC;

    __shared__ float sc[NHEAD][RPC];   // raw scores, then weights

    const float4 q4 = *(const float4*)(q_ws + (size_t)b * NSTATE + col);
    const float* ksrc = kin + base + (size_t)(t0 + 1) * NSTATE + col;
    const float* vsrc = vin + base + (size_t)(t0 + 1) * NSTATE + col;
    float* kdst = kout + base + (size_t)t0 * NSTATE + col;
    float* vdst = vout + base + (size_t)t0 * NSTATE + col;

    // ---- phase 1: K shift-copy + scores (8-deep batches) ----
    {
        int r = 0;
        for (; r + 8 <= nrows; r += 8) {
            f4 kb[8];
            #pragma unroll
            for (int j = 0; j < 8; ++j)
                kb[j] = __builtin_nontemporal_load((const f4*)(ksrc + (size_t)(r + j) * NSTATE));
            #pragma unroll
            for (int j = 0; j < 8; ++j)
                __builtin_nontemporal_store(kb[j], (f4*)(kdst + (size_t)(r + j) * NSTATE));
            #pragma unroll
            for (int j = 0; j < 8; ++j) {
                float p = kb[j][0]*q4.x + kb[j][1]*q4.y + kb[j][2]*q4.z + kb[j][3]*q4.w;
                p += __shfl_xor(p, 1); p += __shfl_xor(p, 2);
                p += __shfl_xor(p, 4); p += __shfl_xor(p, 8);
                if (l == 0) sc[h][r + j] = p + mask[t0 + r + j];
            }
        }
        for (; r < nrows; ++r) {
            f4 kv = __builtin_nontemporal_load((const f4*)(ksrc + (size_t)r * NSTATE));
            __builtin_nontemporal_store(kv, (f4*)(kdst + (size_t)r * NSTATE));
            float p = kv[0]*q4.x + kv[1]*q4.y + kv[2]*q4.z + kv[3]*q4.w;
            p += __shfl_xor(p, 1); p += __shfl_xor(p, 2);
            p += __shfl_xor(p, 4); p += __shfl_xor(p, 8);
            if (l == 0) sc[h][r] = p + mask[t0 + r];
        }
        if (tc == NT - 1) {            // row 447: already final in kout
            const f4 kv = *(const f4*)(kout + base + (size_t)(TCACHE-1) * NSTATE + col);
            float p = kv[0]*q4.x + kv[1]*q4.y + kv[2]*q4.z + kv[3]*q4.w;
            p += __shfl_xor(p, 1); p += __shfl_xor(p, 2);
            p += __shfl_xor(p, 4); p += __shfl_xor(p, 8);
            if (l == 0) sc[h][RPC - 1] = p + mask[TCACHE - 1];
        }
    }
    __syncthreads();

    // ---- phase 2: chunk-local softmax stats + weights ----
    {
        float v[4];
        float m = -1e30f;
        #pragma unroll
        for (int j = 0; j < 4; ++j) {
            int r = l + 16 * j;
            v[j] = (r < RPC) ? sc[h][r] : -1e30f;
            m = fmaxf(m, v[j]);
        }
        #pragma unroll
        for (int d = 1; d <= 8; d <<= 1) m = fmaxf(m, __shfl_xor(m, d));
        float s = 0.f;
        #pragma unroll
        for (int j = 0; j < 4; ++j) {
            v[j] = __expf(v[j] - m);   // pad slots -> 0
            s += v[j];
        }
        #pragma unroll
        for (int d = 1; d <= 8; d <<= 1) s += __shfl_xor(s, d);
        __syncthreads();               // all reads of sc done before overwrite
        #pragma unroll
        for (int j = 0; j < 4; ++j) {
            int r = l + 16 * j;
            if (r < RPC) sc[h][r] = v[j];
        }
        if (l == 0) {
            m_ws[((size_t)b * NT + tc) * NHEAD + h] = m;
            s_ws[((size_t)b * NT + tc) * NHEAD + h] = s;
        }
    }
    __syncthreads();

    // ---- phase 3: V shift-copy + PV partial (8-deep batches) ----
    float ax = 0.f, ay = 0.f, az = 0.f, aw = 0.f;
    {
        int r = 0;
        for (; r + 8 <= nrows; r += 8) {
            f4 vb[8];
            #pragma unroll
            for (int j = 0; j < 8; ++j)
                vb[j] = __builtin_nontemporal_load((const f4*)(vsrc + (size_t)(r + j) * NSTATE));
            #pragma unroll
            for (int j = 0; j < 8; ++j)
                __builtin_nontemporal_store(vb[j], (f4*)(vdst + (size_t)(r + j) * NSTATE));
            #pragma unroll
            for (int j = 0; j < 8; ++j) {
                const float w = sc[h][r + j];
                ax = fmaf(w, vb[j][0], ax); ay = fmaf(w, vb[j][1], ay);
                az = fmaf(w, vb[j][2], az); aw = fmaf(w, vb[j][3], aw);
            }
        }
        for (; r < nrows; ++r) {
            f4 vv = __builtin_nontemporal_load((const f4*)(vsrc + (size_t)r * NSTATE));
            __builtin_nontemporal_store(vv, (f4*)(vdst + (size_t)r * NSTATE));
            const float w = sc[h][r];
            ax = fmaf(w, vv[0], ax); ay = fmaf(w, vv[1], ay);
            az = fmaf(w, vv[2], az); aw = fmaf(w, vv[3], aw);
        }
        if (tc == NT - 1) {            // row 447: already final in vout
            const f4 vv = *(const f4*)(vout + base + (size_t)(TCACHE-1) * NSTATE + col);
            const float w = sc[h][RPC - 1];
            ax = fmaf(w, vv[0], ax); ay = fmaf(w, vv[1], ay);
            az = fmaf(w, vv[2], az); aw = fmaf(w, vv[3], aw);
        }
    }
    *(float4*)(pvp + ((size_t)b * NT + tc) * NSTATE + col) =
        make_float4(ax, ay, az, aw);
}

// ---------------------------------------------------------------------------
// Combine the NT chunk partials with online-softmax rescaling -> wv [128][1280]
// ---------------------------------------------------------------------------
__global__ void __launch_bounds__(256) combine_kernel(
    const float* __restrict__ pvp, const float* __restrict__ m_ws,
    const float* __restrict__ s_ws, float* __restrict__ wv_ws)
{
    const size_t idx = ((size_t)blockIdx.x * 256 + threadIdx.x) * 4;
    const int b = (int)(idx / NSTATE), col = (int)(idx % NSTATE);
    const int h = col >> 6;

    float m[NT], s[NT];
    float M = -1e30f;
    #pragma unroll
    for (int c = 0; c < NT; ++c) {
        m[c] = m_ws[((size_t)b * NT + c) * NHEAD + h];
        s[c] = s_ws[((size_t)b * NT + c) * NHEAD + h];
        M = fmaxf(M, m[c]);
    }
    float S = 0.f;
    float f[NT];
    #pragma unroll
    for (int c = 0; c < NT; ++c) { f[c] = __expf(m[c] - M); S += s[c] * f[c]; }
    const float inv = 1.0f / S;

    float4 acc = make_float4(0.f, 0.f, 0.f, 0.f);
    #pragma unroll
    for (int c = 0; c < NT; ++c) {
        const float w = f[c] * inv;
        float4 a = *(const float4*)(pvp + ((size_t)b * NT + c) * NSTATE + col);
        acc.x = fmaf(w, a.x, acc.x); acc.y = fmaf(w, a.y, acc.y);
        acc.z = fmaf(w, a.z, acc.z); acc.w = fmaf(w, a.w, acc.w);
    }
    *(float4*)(wv_ws + idx) = acc;
}

// output projection partials (MFMA). grid (20, 4): x=n-tile, y=K-split.
__global__ void __launch_bounds__(256) outproj_mfma_kernel(
    const float* __restrict__ wv, const float* __restrict__ Wo,
    float* __restrict__ po)
{
    mfma_partial_body(wv, Wo, po + (size_t)blockIdx.y * NBATCH * NSTATE);
}

__global__ void __launch_bounds__(256) out_reduce_kernel(
    const float* __restrict__ po, const float* __restrict__ bo,
    float* __restrict__ out)
{
    const size_t idx = ((size_t)blockIdx.x * 256 + threadIdx.x) * 4;
    const int col = (int)(idx % NSTATE);
    float4 s = *(const float4*)(bo + col);
    #pragma unroll
    for (int c = 0; c < KSPLIT; ++c) {
        float4 a = *(const float4*)(po + (size_t)c * NBATCH * NSTATE + idx);
        s.x += a.x; s.y += a.y; s.z += a.z; s.w += a.w;
    }
    *(float4*)(out + idx) = s;
}

extern "C" void kernel_launch(void* const* d_in, const int* in_sizes, int n_in,
                              void* d_out, int out_size, void* d_ws, size_t ws_size,
                              hipStream_t stream)
{
    const float* x       = (const float*)d_in[0];
    const float* k_cache = (const float*)d_in[1];
    const float* v_cache = (const float*)d_in[2];
    const float* mask    = (const float*)d_in[3];
    const float* Wq      = (const float*)d_in[4];
    const float* bq      = (const float*)d_in[5];
    const float* Wk      = (const float*)d_in[6];
    const float* Wv      = (const float*)d_in[7];
    const float* bv      = (const float*)d_in[8];
    const float* Wo      = (const float*)d_in[9];
    const float* bo      = (const float*)d_in[10];

    float* out  = (float*)d_out;                                   // [128,1,1280]
    float* kout = out + (size_t)NBATCH * NSTATE;                   // [128,448,1280]
    float* vout = kout + (size_t)NBATCH * TCACHE * NSTATE;         // [128,448,1280]

    float* ws     = (float*)d_ws;
    float* q_ws   = ws;                                            // 163840
    float* pvp_ws = q_ws  + (size_t)NBATCH * NSTATE;               // 1310720
    float* m_ws   = pvp_ws + (size_t)NBATCH * NT * NSTATE;         // 20480
    float* s_ws   = m_ws  + (size_t)NBATCH * NT * NHEAD;           // 20480
    float* wv_ws  = s_ws  + (size_t)NBATCH * NT * NHEAD;           // 163840
    float* pp_ws  = wv_ws + (size_t)NBATCH * NSTATE;               // 12*163840
    float* po_ws  = pp_ws + (size_t)3 * KSPLIT * NBATCH * NSTATE;  // 4*163840

    // 1) q/k/v projection (MFMA split-K partials) + reduce/scatter
    proj_mfma_kernel<<<dim3(20, KSPLIT, 3), 256, 0, stream>>>(x, Wq, Wk, Wv, pp_ws);
    proj_reduce_kernel<<<dim3(160, 3), 256, 0, stream>>>(pp_ws, bq, bv,
                                                         q_ws, kout, vout);
    // 2) fused K/V two-pass stream, 8-deep load batching
    fused_stream_kernel<<<dim3(NT, NBATCH), 320, 0, stream>>>(
        k_cache, v_cache, q_ws, mask, kout, vout, pvp_ws, m_ws, s_ws);
    // 3) combine chunk partials (online-softmax rescale)
    combine_kernel<<<dim3(160), 256, 0, stream>>>(pvp_ws, m_ws, s_ws, wv_ws);
    // 4) output projection (MFMA split-K partials) + reduce with bias
    outproj_mfma_kernel<<<dim3(20, KSPLIT), 256, 0, stream>>>(wv_ws, Wo, po_ws);
    out_reduce_kernel<<<dim3(160), 256, 0, stream>>>(po_ws, bo, out);
}

// Round 10
// 261.175 us; speedup vs baseline: 1.3807x; 1.0202x over previous
//
#include <hip/hip_runtime.h>
#include <cstddef>

#define NSTATE 1280
#define TCACHE 448
#define NBATCH 128
#define NHEAD  20
#define HDIM   64
#define NT     8
#define RPC    (TCACHE / NT)   // 56 rows per chunk
#define KSPLIT 4
#define KRANGE (NSTATE / KSPLIT)   // 320

typedef float f4 __attribute__((ext_vector_type(4)));
typedef float f32x4 __attribute__((ext_vector_type(4)));
typedef short bf16x8 __attribute__((ext_vector_type(8)));
typedef unsigned short u16;
typedef unsigned short u16x8 __attribute__((ext_vector_type(8)));

__device__ __forceinline__ u16 f2bf(float f) {
    unsigned u = __builtin_bit_cast(unsigned, f);
    u += 0x7fff + ((u >> 16) & 1);          // RTN-even (finite inputs)
    return (u16)(u >> 16);
}

// ---------------------------------------------------------------------------
// LDS-staged bf16 MFMA GEMM partial (unchanged from R9):
//   P[128][n0:n0+64] = A_f32[128][kb:kb+320] @ W_f32[kb:kb+320][n0:n0+64]
// ---------------------------------------------------------------------------
__device__ __forceinline__ void mfma_partial_body(
    const float* __restrict__ A, const float* __restrict__ W,
    float* __restrict__ P)
{
    __shared__ u16 As[128][40];
    __shared__ u16 Bs[64][40];
    const int tid = threadIdx.x;
    const int n0 = blockIdx.x * 64;
    const int kb = blockIdx.y * KRANGE;
    const int w = tid >> 6, l = tid & 63;
    const int la = l & 15, kg = l >> 4;
    const int arow = tid >> 1, akh = (tid & 1) << 4;   // A stage: row, k-half
    const int bkr = tid >> 3, bnc = (tid & 7) << 3;    // B stage: k-row, n-chunk
    f32x4 acc[8] = {};

    for (int ks = 0; ks < KRANGE; ks += 32) {
        {
            const float* src = A + (size_t)arow * NSTATE + kb + ks + akh;
            float4 v0 = *(const float4*)(src);
            float4 v1 = *(const float4*)(src + 4);
            float4 v2 = *(const float4*)(src + 8);
            float4 v3 = *(const float4*)(src + 12);
            u16x8 w0, w1;
            w0[0]=f2bf(v0.x); w0[1]=f2bf(v0.y); w0[2]=f2bf(v0.z); w0[3]=f2bf(v0.w);
            w0[4]=f2bf(v1.x); w0[5]=f2bf(v1.y); w0[6]=f2bf(v1.z); w0[7]=f2bf(v1.w);
            w1[0]=f2bf(v2.x); w1[1]=f2bf(v2.y); w1[2]=f2bf(v2.z); w1[3]=f2bf(v2.w);
            w1[4]=f2bf(v3.x); w1[5]=f2bf(v3.y); w1[6]=f2bf(v3.z); w1[7]=f2bf(v3.w);
            *(u16x8*)&As[arow][akh]     = w0;
            *(u16x8*)&As[arow][akh + 8] = w1;
        }
        {
            const float* src = W + (size_t)(kb + ks + bkr) * NSTATE + n0 + bnc;
            float4 b0 = *(const float4*)(src);
            float4 b1 = *(const float4*)(src + 4);
            Bs[bnc + 0][bkr] = f2bf(b0.x); Bs[bnc + 1][bkr] = f2bf(b0.y);
            Bs[bnc + 2][bkr] = f2bf(b0.z); Bs[bnc + 3][bkr] = f2bf(b0.w);
            Bs[bnc + 4][bkr] = f2bf(b1.x); Bs[bnc + 5][bkr] = f2bf(b1.y);
            Bs[bnc + 6][bkr] = f2bf(b1.z); Bs[bnc + 7][bkr] = f2bf(b1.w);
        }
        __syncthreads();
        const bf16x8 bf = *(const bf16x8*)&Bs[w * 16 + la][kg * 8];
        #pragma unroll
        for (int mf = 0; mf < 8; ++mf) {
            bf16x8 af = *(const bf16x8*)&As[mf * 16 + la][kg * 8];
            acc[mf] = __builtin_amdgcn_mfma_f32_16x16x32_bf16(af, bf, acc[mf], 0, 0, 0);
        }
        __syncthreads();
    }
    const int col = n0 + w * 16 + la;
    #pragma unroll
    for (int mf = 0; mf < 8; ++mf)
        #pragma unroll
        for (int j = 0; j < 4; ++j)
            P[(size_t)(mf * 16 + kg * 4 + j) * NSTATE + col] = acc[mf][j];
}

// q/k/v projection partials. grid (20, 4, 3): x=n-tile, y=K-split, z=mat.
__global__ void __launch_bounds__(256) proj_mfma_kernel(
    const float* __restrict__ x,
    const float* __restrict__ Wq, const float* __restrict__ Wk,
    const float* __restrict__ Wv, float* __restrict__ pp)
{
    const int z = blockIdx.z;
    const float* W = (z == 0) ? Wq : (z == 1) ? Wk : Wv;
    mfma_partial_body(x, W,
        pp + (size_t)(z * KSPLIT + blockIdx.y) * NBATCH * NSTATE);
}

// combine proj split-K partials + bias; scatter q->ws (scaled), k/v -> row 447.
__global__ void __launch_bounds__(256) proj_reduce_kernel(
    const float* __restrict__ pp, const float* __restrict__ bq,
    const float* __restrict__ bv, float* __restrict__ q_ws,
    float* __restrict__ kout, float* __restrict__ vout)
{
    const int mat = blockIdx.y;
    const size_t idx = ((size_t)blockIdx.x * 256 + threadIdx.x) * 4;
    const int b = (int)(idx / NSTATE), col = (int)(idx % NSTATE);
    float4 v = make_float4(0.f, 0.f, 0.f, 0.f);
    #pragma unroll
    for (int c = 0; c < KSPLIT; ++c) {
        float4 a = *(const float4*)(pp + (size_t)(mat * KSPLIT + c) * NBATCH * NSTATE + idx);
        v.x += a.x; v.y += a.y; v.z += a.z; v.w += a.w;
    }
    if (mat == 0) {
        float4 bb = *(const float4*)(bq + col);
        v.x = (v.x + bb.x) * 0.125f; v.y = (v.y + bb.y) * 0.125f;
        v.z = (v.z + bb.z) * 0.125f; v.w = (v.w + bb.w) * 0.125f;
        *(float4*)(q_ws + idx) = v;
    } else if (mat == 1) {
        *(float4*)(kout + ((size_t)b * TCACHE + TCACHE - 1) * NSTATE + col) = v;
    } else {
        float4 bb = *(const float4*)(bv + col);
        v.x += bb.x; v.y += bb.y; v.z += bb.z; v.w += bb.w;
        *(float4*)(vout + ((size_t)b * TCACHE + TCACHE - 1) * NSTATE + col) = v;
    }
}

// ---------------------------------------------------------------------------
// Fused stream kernel (two-pass, chunk-local softmax, 8-deep batching) with
// INTERLEAVED row mapping: block (tc,b) handles rows t = tc + NT*r, r<56.
// All NT chunks of a batch sweep the same sliding window together ->
// ~8x fewer concurrent DRAM streams (grid-stride-like locality).
// Chunk-softmax semantics are partition-agnostic; combine unchanged.
// ---------------------------------------------------------------------------
__global__ void __launch_bounds__(320) fused_stream_kernel(
    const float* __restrict__ kin, const float* __restrict__ vin,
    const float* __restrict__ q_ws, const float* __restrict__ mask,
    float* __restrict__ kout, float* __restrict__ vout,
    float* __restrict__ pvp, float* __restrict__ m_ws, float* __restrict__ s_ws)
{
    const int tc = blockIdx.x, b = blockIdx.y;
    const int tid = threadIdx.x;
    const int h = tid >> 4, l = tid & 15;
    const int col = tid << 2;
    const size_t base = (size_t)b * TCACHE * NSTATE;
    const bool last = (tc == NT - 1);
    const int nrows = last ? RPC - 1 : RPC;   // normal (shift-read) rows
    const size_t RSTEP = (size_t)NT * NSTATE; // row stride within the chunk

    __shared__ float sc[NHEAD][RPC];   // raw scores, then weights

    const float4 q4 = *(const float4*)(q_ws + (size_t)b * NSTATE + col);
    // row r -> t = tc + NT*r; read kin row t+1, write kout row t
    const float* ksrc = kin + base + (size_t)(tc + 1) * NSTATE + col;
    const float* vsrc = vin + base + (size_t)(tc + 1) * NSTATE + col;
    float* kdst = kout + base + (size_t)tc * NSTATE + col;
    float* vdst = vout + base + (size_t)tc * NSTATE + col;

    // ---- phase 1: K shift-copy + scores (8-deep batches) ----
    {
        int r = 0;
        for (; r + 8 <= nrows; r += 8) {
            f4 kb[8];
            #pragma unroll
            for (int j = 0; j < 8; ++j)
                kb[j] = __builtin_nontemporal_load((const f4*)(ksrc + (size_t)(r + j) * RSTEP));
            #pragma unroll
            for (int j = 0; j < 8; ++j)
                __builtin_nontemporal_store(kb[j], (f4*)(kdst + (size_t)(r + j) * RSTEP));
            #pragma unroll
            for (int j = 0; j < 8; ++j) {
                float p = kb[j][0]*q4.x + kb[j][1]*q4.y + kb[j][2]*q4.z + kb[j][3]*q4.w;
                p += __shfl_xor(p, 1); p += __shfl_xor(p, 2);
                p += __shfl_xor(p, 4); p += __shfl_xor(p, 8);
                if (l == 0) sc[h][r + j] = p + mask[tc + NT * (r + j)];
            }
        }
        for (; r < nrows; ++r) {
            f4 kv = __builtin_nontemporal_load((const f4*)(ksrc + (size_t)r * RSTEP));
            __builtin_nontemporal_store(kv, (f4*)(kdst + (size_t)r * RSTEP));
            float p = kv[0]*q4.x + kv[1]*q4.y + kv[2]*q4.z + kv[3]*q4.w;
            p += __shfl_xor(p, 1); p += __shfl_xor(p, 2);
            p += __shfl_xor(p, 4); p += __shfl_xor(p, 8);
            if (l == 0) sc[h][r] = p + mask[tc + NT * r];
        }
        if (last) {                    // r=55 -> t=447: already final in kout
            const f4 kv = *(const f4*)(kout + base + (size_t)(TCACHE-1) * NSTATE + col);
            float p = kv[0]*q4.x + kv[1]*q4.y + kv[2]*q4.z + kv[3]*q4.w;
            p += __shfl_xor(p, 1); p += __shfl_xor(p, 2);
            p += __shfl_xor(p, 4); p += __shfl_xor(p, 8);
            if (l == 0) sc[h][RPC - 1] = p + mask[TCACHE - 1];
        }
    }
    __syncthreads();

    // ---- phase 2: chunk-local softmax stats + weights ----
    {
        float v[4];
        float m = -1e30f;
        #pragma unroll
        for (int j = 0; j < 4; ++j) {
            int r = l + 16 * j;
            v[j] = (r < RPC) ? sc[h][r] : -1e30f;
            m = fmaxf(m, v[j]);
        }
        #pragma unroll
        for (int d = 1; d <= 8; d <<= 1) m = fmaxf(m, __shfl_xor(m, d));
        float s = 0.f;
        #pragma unroll
        for (int j = 0; j < 4; ++j) {
            v[j] = __expf(v[j] - m);   // pad slots -> 0
            s += v[j];
        }
        #pragma unroll
        for (int d = 1; d <= 8; d <<= 1) s += __shfl_xor(s, d);
        __syncthreads();               // all reads of sc done before overwrite
        #pragma unroll
        for (int j = 0; j < 4; ++j) {
            int r = l + 16 * j;
            if (r < RPC) sc[h][r] = v[j];
        }
        if (l == 0) {
            m_ws[((size_t)b * NT + tc) * NHEAD + h] = m;
            s_ws[((size_t)b * NT + tc) * NHEAD + h] = s;
        }
    }
    __syncthreads();

    // ---- phase 3: V shift-copy + PV partial (8-deep batches) ----
    float ax = 0.f, ay = 0.f, az = 0.f, aw = 0.f;
    {
        int r = 0;
        for (; r + 8 <= nrows; r += 8) {
            f4 vb[8];
            #pragma unroll
            for (int j = 0; j < 8; ++j)
                vb[j] = __builtin_nontemporal_load((const f4*)(vsrc + (size_t)(r + j) * RSTEP));
            #pragma unroll
            for (int j = 0; j < 8; ++j)
                __builtin_nontemporal_store(vb[j], (f4*)(vdst + (size_t)(r + j) * RSTEP));
            #pragma unroll
            for (int j = 0; j < 8; ++j) {
                const float w = sc[h][r + j];
                ax = fmaf(w, vb[j][0], ax); ay = fmaf(w, vb[j][1], ay);
                az = fmaf(w, vb[j][2], az); aw = fmaf(w, vb[j][3], aw);
            }
        }
        for (; r < nrows; ++r) {
            f4 vv = __builtin_nontemporal_load((const f4*)(vsrc + (size_t)r * RSTEP));
            __builtin_nontemporal_store(vv, (f4*)(vdst + (size_t)r * RSTEP));
            const float w = sc[h][r];
            ax = fmaf(w, vv[0], ax); ay = fmaf(w, vv[1], ay);
            az = fmaf(w, vv[2], az); aw = fmaf(w, vv[3], aw);
        }
        if (last) {                    // r=55 -> t=447: already final in vout
            const f4 vv = *(const f4*)(vout + base + (size_t)(TCACHE-1) * NSTATE + col);
            const float w = sc[h][RPC - 1];
            ax = fmaf(w, vv[0], ax); ay = fmaf(w, vv[1], ay);
            az = fmaf(w, vv[2], az); aw = fmaf(w, vv[3], aw);
        }
    }
    *(float4*)(pvp + ((size_t)b * NT + tc) * NSTATE + col) =
        make_float4(ax, ay, az, aw);
}

// ---------------------------------------------------------------------------
// Combine the NT chunk partials with online-softmax rescaling -> wv [128][1280]
// ---------------------------------------------------------------------------
__global__ void __launch_bounds__(256) combine_kernel(
    const float* __restrict__ pvp, const float* __restrict__ m_ws,
    const float* __restrict__ s_ws, float* __restrict__ wv_ws)
{
    const size_t idx = ((size_t)blockIdx.x * 256 + threadIdx.x) * 4;
    const int b = (int)(idx / NSTATE), col = (int)(idx % NSTATE);
    const int h = col >> 6;

    float m[NT], s[NT];
    float M = -1e30f;
    #pragma unroll
    for (int c = 0; c < NT; ++c) {
        m[c] = m_ws[((size_t)b * NT + c) * NHEAD + h];
        s[c] = s_ws[((size_t)b * NT + c) * NHEAD + h];
        M = fmaxf(M, m[c]);
    }
    float S = 0.f;
    float f[NT];
    #pragma unroll
    for (int c = 0; c < NT; ++c) { f[c] = __expf(m[c] - M); S += s[c] * f[c]; }
    const float inv = 1.0f / S;

    float4 acc = make_float4(0.f, 0.f, 0.f, 0.f);
    #pragma unroll
    for (int c = 0; c < NT; ++c) {
        const float w = f[c] * inv;
        float4 a = *(const float4*)(pvp + ((size_t)b * NT + c) * NSTATE + col);
        acc.x = fmaf(w, a.x, acc.x); acc.y = fmaf(w, a.y, acc.y);
        acc.z = fmaf(w, a.z, acc.z); acc.w = fmaf(w, a.w, acc.w);
    }
    *(float4*)(wv_ws + idx) = acc;
}

// output projection partials (MFMA). grid (20, 4): x=n-tile, y=K-split.
__global__ void __launch_bounds__(256) outproj_mfma_kernel(
    const float* __restrict__ wv, const float* __restrict__ Wo,
    float* __restrict__ po)
{
    mfma_partial_body(wv, Wo, po + (size_t)blockIdx.y * NBATCH * NSTATE);
}

__global__ void __launch_bounds__(256) out_reduce_kernel(
    const float* __restrict__ po, const float* __restrict__ bo,
    float* __restrict__ out)
{
    const size_t idx = ((size_t)blockIdx.x * 256 + threadIdx.x) * 4;
    const int col = (int)(idx % NSTATE);
    float4 s = *(const float4*)(bo + col);
    #pragma unroll
    for (int c = 0; c < KSPLIT; ++c) {
        float4 a = *(const float4*)(po + (size_t)c * NBATCH * NSTATE + idx);
        s.x += a.x; s.y += a.y; s.z += a.z; s.w += a.w;
    }
    *(float4*)(out + idx) = s;
}

extern "C" void kernel_launch(void* const* d_in, const int* in_sizes, int n_in,
                              void* d_out, int out_size, void* d_ws, size_t ws_size,
                              hipStream_t stream)
{
    const float* x       = (const float*)d_in[0];
    const float* k_cache = (const float*)d_in[1];
    const float* v_cache = (const float*)d_in[2];
    const float* mask    = (const float*)d_in[3];
    const float* Wq      = (const float*)d_in[4];
    const float* bq      = (const float*)d_in[5];
    const float* Wk      = (const float*)d_in[6];
    const float* Wv      = (const float*)d_in[7];
    const float* bv      = (const float*)d_in[8];
    const float* Wo      = (const float*)d_in[9];
    const float* bo      = (const float*)d_in[10];

    float* out  = (float*)d_out;                                   // [128,1,1280]
    float* kout = out + (size_t)NBATCH * NSTATE;                   // [128,448,1280]
    float* vout = kout + (size_t)NBATCH * TCACHE * NSTATE;         // [128,448,1280]

    float* ws     = (float*)d_ws;
    float* q_ws   = ws;                                            // 163840
    float* pvp_ws = q_ws  + (size_t)NBATCH * NSTATE;               // 1310720
    float* m_ws   = pvp_ws + (size_t)NBATCH * NT * NSTATE;         // 20480
    float* s_ws   = m_ws  + (size_t)NBATCH * NT * NHEAD;           // 20480
    float* wv_ws  = s_ws  + (size_t)NBATCH * NT * NHEAD;           // 163840
    float* pp_ws  = wv_ws + (size_t)NBATCH * NSTATE;               // 12*163840
    float* po_ws  = pp_ws + (size_t)3 * KSPLIT * NBATCH * NSTATE;  // 4*163840

    // 1) q/k/v projection (MFMA split-K partials) + reduce/scatter
    proj_mfma_kernel<<<dim3(20, KSPLIT, 3), 256, 0, stream>>>(x, Wq, Wk, Wv, pp_ws);
    proj_reduce_kernel<<<dim3(160, 3), 256, 0, stream>>>(pp_ws, bq, bv,
                                                         q_ws, kout, vout);
    // 2) fused K/V two-pass stream, interleaved row mapping
    fused_stream_kernel<<<dim3(NT, NBATCH), 320, 0, stream>>>(
        k_cache, v_cache, q_ws, mask, kout, vout, pvp_ws, m_ws, s_ws);
    // 3) combine chunk partials (online-softmax rescale)
    combine_kernel<<<dim3(160), 256, 0, stream>>>(pvp_ws, m_ws, s_ws, wv_ws);
    // 4) output projection (MFMA split-K partials) + reduce with bias
    outproj_mfma_kernel<<<dim3(20, KSPLIT), 256, 0, stream>>>(wv_ws, Wo, po_ws);
    out_reduce_kernel<<<dim3(160), 256, 0, stream>>>(po_ws, bo, out);
}